// Round 14
// baseline (92.220 us; speedup 1.0000x reference)
//
#include <hip/hip_runtime.h>

#define BATCH   16384
#define NUM_NUM 32
#define NUM_CAT 32
#define CARD    128
#define OUT_F   32
#define XSTRIDE 4128   // NUM_NUM + NUM_CAT*CARD
#define OSTRIDE 1056   // NUM_NUM + NUM_CAT*OUT_F

#define TRB    64              // rows per block
#define CK     32              // K cols per chunk (128B staged segments)
#define NCHUNK (CARD / CK)     // 4
#define QPW    512             // quads per wave-private buffer (8 KB)

typedef const __attribute__((address_space(1))) void* as1_cvp;
typedef __attribute__((address_space(3))) void*       as3_vp;

// FREE-RUNNING WAVES: no __syncthreads in the main loop. Each wave stages ALL
// 64 rows x CK into its OWN 8KB LDS buffer (4x duplicate issue; dedups in
// L1/L2 - HBM traffic unchanged) and privately waits vmcnt(0). 5 blocks/CU x
// 4 waves = 20 DE-CORRELATED waves (r13 post-mortem: barrier convoy, not
// bandwidth, was the 85us floor; independent 30-40% duty waves fill the SIMD).
// Wave og owns outs [og*8,+8) -> W/bias wave-uniform s_load (SMEM pipe).
// Lane = row. Swizzle identical to r11/r13 (proven): stage phys P=i*64+l holds
// row i*8+(l>>3), cq (l&7)^((l>>3)&7); read addr l*8+(c4^(l&7)) (~1.33x bank
// cost accepted). Ordering: lgkmcnt(0) clobber-asm before restage (own
// ds_reads drained before overwrite); vmcnt(0) clobber-asm before ds_reads
// (ds ops are memory ops -> the clobber orders them; rule-18 is MFMA-only).
// Epilogue (2 barriers total, block end): LDS transpose -> 128B/row stores.
__global__ __launch_bounds__(256, 5) void emb_free(const float* __restrict__ x,
                                                   const float* __restrict__ Wm,
                                                   const float* __restrict__ bias,
                                                   float* __restrict__ out) {
    __shared__ float4 lds[4 * QPW];  // 32 KB: one 8KB buffer per wave; ctr = [0,512)

    const int f    = blockIdx.x;
    const int row0 = blockIdx.y * TRB;
    const int tid  = threadIdx.x;
    const int l    = tid & 63;
    const int lx   = l & 7;
    const int og   = __builtin_amdgcn_readfirstlane(tid >> 6);  // wave id = out-group

    const float* xg   = x + (size_t)row0 * XSTRIDE + NUM_NUM + f * CARD;
    const int    srow = l >> 3;                    // stage: row-within-8
    const int    scq  = (l & 7) ^ ((l >> 3) & 7);  // stage: inverse-swizzled col-quad

    // stage chunk ck into THIS wave's buffer: 8 gload_lds, rows i*8..i*8+8 each
#define STAGE(ck)                                                                        \
    {                                                                                    \
        _Pragma("unroll") for (int i = 0; i < 8; ++i) {                                  \
            __builtin_amdgcn_global_load_lds(                                            \
                (as1_cvp)(xg + (size_t)(i * 8 + srow) * XSTRIDE + (ck) * CK + scq * 4),  \
                (as3_vp)&lds[og * QPW + i * 64 + l], 16, 0, 0);                          \
        }                                                                                \
    }

    // wave-uniform W quad pointer: wq[c*8], wq[c*8+1] = W[f][c][og*8 .. +8)
    const float4* __restrict__ wq =
        (const float4*)Wm + ((size_t)f * (CARD * OUT_F / 4) + og * 2);

    float acc[8];
#pragma unroll
    for (int k = 0; k < 8; ++k) acc[k] = 0.0f;

    for (int ck = 0; ck < NCHUNK; ++ck) {
        // own ds_reads of the previous chunk are long done; drain before overwrite
        asm volatile("s_waitcnt lgkmcnt(0)" ::: "memory");
        STAGE(ck);
        asm volatile("s_waitcnt vmcnt(0)" ::: "memory");  // wave-private wait, no barrier

#pragma unroll
        for (int h = 0; h < 2; ++h) {
            float4 xv[4];
#pragma unroll
            for (int c4 = 0; c4 < 4; ++c4)
                xv[c4] = lds[og * QPW + l * 8 + ((h * 4 + c4) ^ lx)];

#pragma unroll
            for (int c4 = 0; c4 < 4; ++c4) {
#pragma unroll
                for (int cc = 0; cc < 4; ++cc) {
                    const int    c  = ck * CK + (h * 4 + c4) * 4 + cc;
                    const float4 wa = wq[c * 8];      // s_load_dwordx4 (uniform)
                    const float4 wb = wq[c * 8 + 1];
                    const float  xf = (&xv[c4].x)[cc];
                    acc[0] += xf * wa.x;  acc[1] += xf * wa.y;
                    acc[2] += xf * wa.z;  acc[3] += xf * wa.w;
                    acc[4] += xf * wb.x;  acc[5] += xf * wb.y;
                    acc[6] += xf * wb.z;  acc[7] += xf * wb.w;
                }
            }
        }
    }

    __syncthreads();  // first block-wide barrier: all waves done with their buffers

    // ---- epilogue: bias (uniform) + transpose through ctr = lds[0,512) ----
    const float4 b0 = ((const float4*)bias)[f * 8 + og * 2];
    const float4 b1 = ((const float4*)bias)[f * 8 + og * 2 + 1];
    lds[l * 8 + ((og * 2) ^ lx)] =
        make_float4(acc[0] + b0.x, acc[1] + b0.y, acc[2] + b0.z, acc[3] + b0.w);
    lds[l * 8 + ((og * 2 + 1) ^ lx)] =
        make_float4(acc[4] + b1.x, acc[5] + b1.y, acc[6] + b1.z, acc[7] + b1.w);
    __syncthreads();

    // coalesced stores: 4 threads cover one row's 128B
    {
        const int    r  = tid >> 2;
        const int    qp = (tid & 3) * 2;
        const float4 v0 = lds[r * 8 + (qp ^ (r & 7))];
        const float4 v1 = lds[r * 8 + ((qp + 1) ^ (r & 7))];
        float* orow = out + (size_t)(row0 + r) * OSTRIDE + NUM_NUM + f * OUT_F + qp * 4;
        *(float4*)(orow)     = v0;
        *(float4*)(orow + 4) = v1;
    }

    // ---- numeric passthrough: distributed across f = (stripe & 31) ----
    if (f == (blockIdx.y & 31)) {
#pragma unroll
        for (int it = 0; it < 2; ++it) {
            const int idx = it * 256 + tid;  // 512 float4
            const int r   = idx >> 3;
            const int c4  = (idx & 7) << 2;
            *(float4*)(out + (size_t)(row0 + r) * OSTRIDE + c4) =
                *(const float4*)(x + (size_t)(row0 + r) * XSTRIDE + c4);
        }
    }
#undef STAGE
}

extern "C" void kernel_launch(void* const* d_in, const int* in_sizes, int n_in,
                              void* d_out, int out_size, void* d_ws, size_t ws_size,
                              hipStream_t stream) {
    const float* x    = (const float*)d_in[0];
    const float* W    = (const float*)d_in[1];
    const float* bias = (const float*)d_in[2];
    float*       out  = (float*)d_out;

    dim3 grid(NUM_CAT, BATCH / TRB);  // (32, 256), f fastest
    emb_free<<<grid, 256, 0, stream>>>(x, W, bias, out);
}

// Round 15
// 78.137 us; speedup vs baseline: 1.1802x; 1.1802x over previous
//
#include <hip/hip_runtime.h>
#include <stdint.h>

#define BATCH   16384
#define NUM_NUM 32
#define NUM_CAT 32
#define CARD    128
#define OUT_F   32
#define XSTRIDE 4128   // NUM_NUM + NUM_CAT*CARD
#define OSTRIDE 1056   // NUM_NUM + NUM_CAT*OUT_F

typedef __attribute__((ext_vector_type(8))) short short8;  // 8 bf16 (guide §3 frag type)
typedef __attribute__((ext_vector_type(4))) float f32x4;

// f32 -> bf16, round-to-nearest-even, pure bit ops (no header API risk).
__device__ __forceinline__ unsigned short f2bf(float f) {
    unsigned u = __builtin_bit_cast(unsigned, f);
    return (unsigned short)((u + 0x7FFFu + ((u >> 16) & 1u)) >> 16);
}

// MFMA formulation: per f, C(16384x32) = A(16384x128)*B(128x32), bf16 in / f32 acc.
// Block = (f, 256 rows); wave wv owns 64 rows = 4 M-tiles of 16. NO LDS, NO barriers.
// A-frag: lane l holds A[row=l&15][k=(l>>4)*8+i] -> direct global 2x dwordx4/lane;
//   per instr the wave covers 16 rows' FULL 128B lines (r13 granule, no staging).
// B-frag: lane l holds B[k=(l>>4)*8+i][col=l&15] <- W[f][k][o] strided dword loads,
//   one-time per block, L2-hot (64 blocks/f share). Same k-map as A -> any k-layout
//   error cancels (permutation applied to both operands feeds matching slots).
// C/D: col=l&15, row=(l>>4)*4+reg [HW-verified m89/m91]. VALU floor (27us) GONE:
// matrix pipe does the math; kernel is a pure streaming loader like a copy kernel.
__global__ __launch_bounds__(256, 4) void emb_mfma(const float* __restrict__ x,
                                                   const float* __restrict__ Wm,
                                                   const float* __restrict__ bias,
                                                   float* __restrict__ out) {
    const int f    = blockIdx.x;
    const int row0 = blockIdx.y * 256;
    const int tid  = threadIdx.x;
    const int l    = tid & 63;
    const int wv   = tid >> 6;
    const int lr   = l & 15;   // A-row / B-col / D-col
    const int lg   = l >> 4;   // k-group (8 elems each)

    // ---- B fragments: W[f] -> bf16 VGPRs, 2 n-tiles x 4 k-frags (one-time) ----
    const float* wf = Wm + (size_t)f * (CARD * OUT_F);
    short8 bw[2][4];
#pragma unroll
    for (int n = 0; n < 2; ++n)
#pragma unroll
        for (int kf = 0; kf < 4; ++kf)
#pragma unroll
            for (int i = 0; i < 8; ++i)
                bw[n][kf][i] = (short)f2bf(wf[(kf * 32 + lg * 8 + i) * OUT_F + n * 16 + lr]);

    const float bias0 = bias[f * OUT_F + lr];
    const float bias1 = bias[f * OUT_F + 16 + lr];

    const float* xf    = x + NUM_NUM + f * CARD;
    float*       obase = out + NUM_NUM + f * OUT_F;

#pragma unroll
    for (int m = 0; m < 4; ++m) {
        const int    mrow = row0 + wv * 64 + m * 16 + lr;
        const float* xr   = xf + (size_t)mrow * XSTRIDE;

        f32x4 acc0 = {0.f, 0.f, 0.f, 0.f};
        f32x4 acc1 = {0.f, 0.f, 0.f, 0.f};
#pragma unroll
        for (int kf = 0; kf < 4; ++kf) {
            const float4 v0 = *(const float4*)(xr + kf * 32 + lg * 8);
            const float4 v1 = *(const float4*)(xr + kf * 32 + lg * 8 + 4);
            short8 af;
            af[0] = (short)f2bf(v0.x); af[1] = (short)f2bf(v0.y);
            af[2] = (short)f2bf(v0.z); af[3] = (short)f2bf(v0.w);
            af[4] = (short)f2bf(v1.x); af[5] = (short)f2bf(v1.y);
            af[6] = (short)f2bf(v1.z); af[7] = (short)f2bf(v1.w);
            acc0 = __builtin_amdgcn_mfma_f32_16x16x32_bf16(af, bw[0][kf], acc0, 0, 0, 0);
            acc1 = __builtin_amdgcn_mfma_f32_16x16x32_bf16(af, bw[1][kf], acc1, 0, 0, 0);
        }

        // D: row = (l>>4)*4 + r, col = lr. Per instr: 4 rows x 64B segments;
        // acc0/acc1 halves of each row's 128B line merge in L2.
#pragma unroll
        for (int r = 0; r < 4; ++r) {
            const size_t orow = (size_t)(row0 + wv * 64 + m * 16 + lg * 4 + r) * OSTRIDE;
            obase[orow + lr]      = acc0[r] + bias0;
            obase[orow + 16 + lr] = acc1[r] + bias1;
        }
    }

    // ---- numeric passthrough: one block per stripe (f == stripe&31), row/thread ----
    if (f == (blockIdx.y & 31)) {
        const float4* src = (const float4*)(x + (size_t)(row0 + tid) * XSTRIDE);
        float4*       dst = (float4*)(out + (size_t)(row0 + tid) * OSTRIDE);
#pragma unroll
        for (int q = 0; q < 8; ++q) dst[q] = src[q];
    }
}

extern "C" void kernel_launch(void* const* d_in, const int* in_sizes, int n_in,
                              void* d_out, int out_size, void* d_ws, size_t ws_size,
                              hipStream_t stream) {
    const float* x    = (const float*)d_in[0];
    const float* W    = (const float*)d_in[1];
    const float* bias = (const float*)d_in[2];
    float*       out  = (float*)d_out;

    dim3 grid(NUM_CAT, BATCH / 256);  // (32, 64), f fastest
    emb_mfma<<<grid, 256, 0, stream>>>(x, W, bias, out);
}